// Round 17
// baseline (602.270 us; speedup 1.0000x reference)
//
#include <hip/hip_runtime.h>
#include <hip/hip_bf16.h>
#include <stdint.h>

// Problem dims (fixed by setup_inputs)
#define B_    4
#define N_    16384
#define M_    4096
#define C1_   64
#define C2_   256
#define CIN_  320   // C2 + C1 (concat order: [interp(256), fine(64)])
#define H1_   256
#define H2_   128
#define ROWS_ (B_*N_)   // 65536
#define SPLIT_ 1
#define NBIN_ 4160      // 4097 lo-bins (0..4096), padded

typedef __attribute__((ext_vector_type(8))) short bf16x8;
typedef __attribute__((ext_vector_type(4))) float f32x4;
typedef __attribute__((ext_vector_type(8))) unsigned short u16x8;
typedef __attribute__((ext_vector_type(4))) unsigned short u16x4;

static __device__ __forceinline__ unsigned short f2bf(float f) {
  union { float f; unsigned u; } v; v.f = f;
  unsigned r = v.u + 0x7fffu + ((v.u >> 16) & 1u);
  return (unsigned short)(r >> 16);
}
static __device__ __forceinline__ float bf2f(unsigned short h) {
  union { unsigned u; float f; } v; v.u = ((unsigned)h) << 16;
  return v.f;
}

// async global->LDS, 16B per lane. lds base must be wave-uniform.
static __device__ __forceinline__ void gload16(const void* g, void* lds) {
  __builtin_amdgcn_global_load_lds(
      (__attribute__((address_space(1))) void*)(uintptr_t)g,
      (__attribute__((address_space(3))) void*)(uintptr_t)lds,
      16, 0, 0);
}

// strict-< top-3 insert (merge): ties keep the earlier entry.
#define INS3(dv, iv) do {                                        \
  float _d = (dv); int _ii = (iv);                               \
  if (_d < d3) {                                                 \
    if (_d < d2) {                                               \
      d3 = d2; i3 = i2;                                          \
      if (_d < d1) { d2 = d1; i2 = i1; d1 = _d; i1 = _ii; }      \
      else         { d2 = _d; i2 = _ii; }                        \
    } else { d3 = _d; i3 = _ii; }                                \
  } } while (0)

// ---------------- kernel 0: weights + coarse feats -> bf16, pts -> float4 --
__global__ __launch_bounds__(256) void prep(
    const float* __restrict__ W1, const float* __restrict__ W2,
    const float* __restrict__ xyzc, const float* __restrict__ fc,
    unsigned short* __restrict__ W1b, unsigned short* __restrict__ W2b,
    float4* __restrict__ cpk, unsigned short* __restrict__ fcb)
{
  int i = blockIdx.x * 256 + threadIdx.x;
  if (i < H1_*CIN_) W1b[i] = f2bf(W1[i]);
  if (i < H2_*H1_)  W2b[i] = f2bf(W2[i]);
  if (i < B_*M_) {
    float x = xyzc[i*3], y = xyzc[i*3+1], z = xyzc[i*3+2];
    cpk[i] = make_float4(x, y, z, x*x + y*y + z*z);
  }
  const int total4 = B_*M_*C2_/4;
  const int stride = gridDim.x * 256;
  for (int t = i; t < total4; t += stride) {
    float4 v = ((const float4*)fc)[t];
    u16x4 o;
    o[0] = f2bf(v.x); o[1] = f2bf(v.y); o[2] = f2bf(v.z); o[3] = f2bf(v.w);
    ((u16x4*)fcb)[t] = o;
  }
}

// ---------------- kernel 1: bitonic sort coarse points by x (validated R15)
__global__ __launch_bounds__(1024) void sort_coarse(
    const float4* __restrict__ cpk,
    float* __restrict__ sxs, float4* __restrict__ cps)
{
  __shared__ unsigned long long key[M_];
  const int b = blockIdx.x;
  const int tid = threadIdx.x;
  for (int i = tid; i < M_; i += 1024) {
    unsigned ux = __float_as_uint(cpk[(size_t)b*M_ + i].x);
    ux ^= (ux >> 31) ? 0xFFFFFFFFu : 0x80000000u;   // monotone float->u32
    key[i] = ((unsigned long long)ux << 32) | (unsigned)i;
  }
  __syncthreads();
  for (int k = 2; k <= M_; k <<= 1) {
    for (int j = k >> 1; j > 0; j >>= 1) {
      for (int i = tid; i < M_; i += 1024) {
        int ixj = i ^ j;
        if (ixj > i) {
          unsigned long long a = key[i], c = key[ixj];
          bool up = ((i & k) == 0);
          if ((a > c) == up) { key[i] = c; key[ixj] = a; }
        }
      }
      __syncthreads();
    }
  }
  for (int i = tid; i < M_; i += 1024) {
    int idx = (int)(unsigned)key[i];            // low 32 bits
    float4 c = cpk[(size_t)b*M_ + idx];
    sxs[(size_t)b*M_ + i] = c.x;
    cps[(size_t)b*M_ + i] = make_float4(c.x, c.y, c.z, __int_as_float(idx));
  }
}

// ---------------- kernel 2a: per-fine-point lo (binary search) + histogram -
// grid: B*64 x 256. Stages sxs (16KB). lov[gp]=lo; hist[b][lo]++ (atomic).
__global__ __launch_bounds__(256) void lo_hist(
    const float* __restrict__ xyzf, const float* __restrict__ sxs,
    int* __restrict__ lov, int* __restrict__ hist)
{
  __shared__ float sx_l[M_];
  const int tid  = threadIdx.x;
  const int tile = blockIdx.x & 63;
  const int b    = blockIdx.x >> 6;
  const float4* srcx = (const float4*)(sxs + (size_t)b * M_);
  for (int i = tid; i < M_/4; i += 256) ((float4*)sx_l)[i] = srcx[i];
  __syncthreads();
  const int p = tile * 256 + tid;
  const size_t gp = (size_t)b * N_ + p;
  const float px = xyzf[gp * 3];
  int lo = 0, hi = M_;
  while (lo < hi) { int mid = (lo + hi) >> 1; if (sx_l[mid] < px) lo = mid + 1; else hi = mid; }
  lov[gp] = lo;
  atomicAdd(&hist[b * NBIN_ + lo], 1);
}

// ---------------- kernel 2b: exclusive prefix over 4097 bins (1 wave/batch)
__global__ __launch_bounds__(64) void prefix_bins(
    const int* __restrict__ hist, int* __restrict__ offs)
{
  const int b = blockIdx.x, t = threadIdx.x;
  const int PER = 65;                    // 64*65 = 4160 covers 0..4096
  int s = 0;
  for (int k = 0; k < PER; ++k) {
    int idx = t * PER + k;
    s += (idx <= M_) ? hist[b * NBIN_ + idx] : 0;
  }
  int incl = s;
  #pragma unroll
  for (int o = 1; o < 64; o <<= 1) {
    int v = __shfl_up(incl, o);
    if (t >= o) incl += v;
  }
  int run = incl - s;                    // exclusive base for this lane's chunk
  for (int k = 0; k < PER; ++k) {
    int idx = t * PER + k;
    if (idx <= M_) {
      int h = hist[b * NBIN_ + idx];
      offs[b * NBIN_ + idx] = run;
      run += h;
    }
  }
}

// ---------------- kernel 2c: scatter -> perm (lo-sorted fine point list) ---
// perm entry = (point_idx << 13) | lo. Order within a bin is atomic-order
// (nondeterministic) but provably does not affect output (see nn_bucket).
__global__ __launch_bounds__(256) void scatter_perm(
    const int* __restrict__ lov, int* __restrict__ offs,
    unsigned* __restrict__ perm)
{
  const int tid  = threadIdx.x;
  const int tile = blockIdx.x & 63;
  const int b    = blockIdx.x >> 6;
  const int p    = tile * 256 + tid;
  const size_t gp = (size_t)b * N_ + p;
  int lo = lov[gp];
  int pos = atomicAdd(&offs[b * NBIN_ + lo], 1);
  perm[(size_t)b * N_ + pos] = ((unsigned)p << 13) | (unsigned)lo;
}

// ---------------- kernel 3: 3-NN, wave-uniform window scan over sorted x ---
// grid: B*64 x 256 (each block: 256 lo-sorted fine points; 4 waves).
// All candidates staged in LDS (64KB). j loops are WAVE-UNIFORM (lo-spread
// within a wave ~16 after counting sort): cl[j] is a broadcast read (no
// conflicts), no per-lane latency chains (R15's failure mode). Partition:
// right scan takes j>=lo ascending, left takes j<lo descending; inserts are
// exact strict-< so extra scanned candidates are provably rejected =>
// output independent of wave grouping. Early exit via __all(dx^2>=D3),
// checked every 4 candidates (stop flag is monotone per lane).
__global__ __launch_bounds__(256) void nn_bucket(
    const float* __restrict__ xyzf, const float4* __restrict__ cps,
    const unsigned* __restrict__ perm,
    float4* __restrict__ pdw, int4* __restrict__ piw)
{
  __shared__ float4 cl[M_];              // 64KB: (x,y,z, idx-bits) sorted by x
  const int tid = threadIdx.x;
  const int blk = blockIdx.x & 63;
  const int b   = blockIdx.x >> 6;
  const float4* src = cps + (size_t)b * M_;
  for (int i = tid; i < M_; i += 256) cl[i] = src[i];
  __syncthreads();

  unsigned e = perm[(size_t)b * N_ + blk * 256 + tid];
  const int ip = (int)(e >> 13);
  const int lo = (int)(e & 8191u);
  const size_t gp = (size_t)b * N_ + ip;
  const float px = xyzf[gp*3], py = xyzf[gp*3+1], pz = xyzf[gp*3+2];

  int wmin = lo, wmax = lo;
  #pragma unroll
  for (int o = 1; o < 64; o <<= 1) {
    wmin = min(wmin, __shfl_xor(wmin, o));
    wmax = max(wmax, __shfl_xor(wmax, o));
  }

  float D1 = 3.4e38f, D2 = 3.4e38f, D3 = 3.4e38f;
  int   I1 = 0, I2 = 0, I3 = 0;

#define TRYI(c, mine) do {                                                \
    float ax = (c).x - px, ay = (c).y - py, az = (c).z - pz;              \
    float d = fmaf(ax, ax, fmaf(ay, ay, az * az));                        \
    int idx = __float_as_int((c).w);                                      \
    if ((mine) && d < D3) {                                               \
      bool c1 = d < D1, c2 = d < D2;                                      \
      D3 = c2 ? D2 : d;             I3 = c2 ? I2 : idx;                   \
      D2 = c1 ? D1 : (c2 ? d : D2); I2 = c1 ? I1 : (c2 ? idx : I2);       \
      D1 = c1 ? d  : D1;            I1 = c1 ? idx : I1;                   \
    } } while (0)

  // right: j >= lo, ascending (uniform j)
  #pragma unroll 1
  for (int j0 = wmin; j0 < M_; j0 += 4) {
    bool stop = false;
    #pragma unroll
    for (int u = 0; u < 4; ++u) {
      int j = j0 + u;
      if (j < M_) {                      // uniform branch
        float4 c = cl[j];
        bool mine = j >= lo;
        TRYI(c, mine);
        float dx = c.x - px;
        stop = mine && (dx * dx >= D3);
      }
    }
    if (__all(stop)) break;
  }
  // left: j < lo, descending (uniform j)
  #pragma unroll 1
  for (int j0 = wmax - 1; j0 >= 0; j0 -= 4) {
    bool stop = false;
    #pragma unroll
    for (int u = 0; u < 4; ++u) {
      int j = j0 - u;
      if (j >= 0) {
        float4 c = cl[j];
        bool mine = j < lo;
        TRYI(c, mine);
        float dx = c.x - px;
        stop = mine && (dx * dx >= D3);
      }
    }
    if (__all(stop)) break;
  }
#undef TRYI

  pdw[gp] = make_float4(D1, D2, D3, 0.f);
  piw[gp] = make_int4(I1, I2, I3, 0);
}

// ---------------- kernel 4: merge(single) + weights + interp + concat ------
__global__ __launch_bounds__(256) void nn_finish(
    const float4* __restrict__ pdw, const int4* __restrict__ piw,
    const float* __restrict__ ff, const unsigned short* __restrict__ fcb,
    unsigned short* __restrict__ X)
{
  __shared__ float wv[64][3];
  __shared__ int   wi[64][3];
  const int tid  = threadIdx.x;
  const int b    = blockIdx.x >> 8;
  const int tile = blockIdx.x & 255;
  const size_t gp0 = (size_t)b * N_ + tile * 64;

  if (tid < 64) {
    const size_t gp = gp0 + tid;
    float d1 = 3.4e38f, d2 = 3.4e38f, d3 = 3.4e38f;
    int   i1 = 0, i2 = 0, i3 = 0;
    #pragma unroll
    for (int s = 0; s < SPLIT_; ++s) {
      float4 dv = pdw[(size_t)s * ROWS_ + gp];
      int4   iv = piw[(size_t)s * ROWS_ + gp];
      INS3(dv.x, iv.x);
      INS3(dv.y, iv.y);
      INS3(dv.z, iv.z);
    }
    d1 = fmaxf(d1, 1e-10f); d2 = fmaxf(d2, 1e-10f); d3 = fmaxf(d3, 1e-10f);
    float u1 = 1.f/d1, u2 = 1.f/d2, u3 = 1.f/d3;
    float inv = 1.f/(u1 + u2 + u3);
    wv[tid][0] = u1*inv; wv[tid][1] = u2*inv; wv[tid][2] = u3*inv;
    wi[tid][0] = i1;     wi[tid][1] = i2;     wi[tid][2] = i3;
  }
  __syncthreads();

  const int w = tid >> 6, l = tid & 63;
  const unsigned short* fcb_b = fcb + (size_t)b * M_ * C2_;
  unsigned short* Xb = X + gp0 * CIN_;
  #pragma unroll 2
  for (int q = 0; q < 16; ++q) {
    int pl = w * 16 + q;
    float a1 = wv[pl][0], a2 = wv[pl][1], a3 = wv[pl][2];
    int   j1 = wi[pl][0], j2 = wi[pl][1], j3 = wi[pl][2];
    u16x4 r1 = ((const u16x4*)(fcb_b + (size_t)j1 * C2_))[l];
    u16x4 r2 = ((const u16x4*)(fcb_b + (size_t)j2 * C2_))[l];
    u16x4 r3 = ((const u16x4*)(fcb_b + (size_t)j3 * C2_))[l];
    u16x4 o;
    #pragma unroll
    for (int e = 0; e < 4; ++e) {
      float v = fmaf(a1, bf2f(r1[e]), fmaf(a2, bf2f(r2[e]), a3 * bf2f(r3[e])));
      o[e] = f2bf(v);
    }
    *(u16x4*)(Xb + (size_t)pl * CIN_ + l * 4) = o;
  }

  {
    const float* ffb = ff + gp0 * C1_;
    int pl = tid >> 2, c0 = (tid & 3) * 16;
    const float4* fsrc = (const float4*)(ffb + (size_t)pl * C1_ + c0);
    unsigned short* dst = Xb + (size_t)pl * CIN_ + C2_ + c0;
    #pragma unroll
    for (int t = 0; t < 4; ++t) {
      float4 v = fsrc[t];
      u16x4 o;
      o[0] = f2bf(v.x); o[1] = f2bf(v.y); o[2] = f2bf(v.z); o[3] = f2bf(v.w);
      *(u16x4*)(dst + t * 4) = o;
    }
  }
}

// ---------------- GEMM: C[M][NTOT] = A[M][K] * Bw[NTOT][K]^T + col stats ---
template<int K, int NTOT, bool OUTBF>
__global__ __launch_bounds__(256) void gemm_stats(
    const unsigned short* __restrict__ A,
    const unsigned short* __restrict__ Bw,
    unsigned short* __restrict__ Yb,
    float* __restrict__ Yf,
    float* __restrict__ part)
{
  constexpr int BM = 128, BN = 128, BK = 64;
  constexpr int NCT = NTOT / BN;
  __shared__ unsigned short As[BM*BK];
  __shared__ unsigned short Bs[BN*BK];
  __shared__ float sred[2][BN][2];

  const int tid = threadIdx.x;
  const int l   = tid & 63;
  const int w   = tid >> 6;
  const int wm  = w >> 1, wn = w & 1;
  int rt, ct;
  if (NCT == 2) {
    rt = (blockIdx.x & 7) | ((blockIdx.x >> 4) << 3);
    ct = (blockIdx.x >> 3) & 1;
  } else {
    rt = blockIdx.x / NCT; ct = blockIdx.x % NCT;
  }
  const int lr  = l & 15;
  const int lk  = (l >> 4) * 8;

  const unsigned short* Arow = A  + (size_t)rt * BM * K;
  const unsigned short* Brow = Bw + (size_t)ct * BN * K;

  f32x4 acc[4][4] = {};

  for (int k0 = 0; k0 < K; k0 += BK) {
    #pragma unroll
    for (int q = 0; q < 4; ++q) {
      int chunk = q * 256 + tid;
      int row = chunk >> 3, cc = chunk & 7;
      unsigned ldsoff = (unsigned)(q * 256 + (tid & ~63)) * 16u;   // wave-uniform
      gload16(Arow + (size_t)row * K + k0 + cc * 8, (char*)As + ldsoff);
      gload16(Brow + (size_t)row * K + k0 + cc * 8, (char*)Bs + ldsoff);
    }
    __syncthreads();
    #pragma unroll
    for (int kk = 0; kk < BK/32; ++kk) {
      bf16x8 af[4], bfr[4];
      #pragma unroll
      for (int m = 0; m < 4; ++m)
        af[m] = *(const bf16x8*)(As + (wm*64 + m*16 + lr)*BK + kk*32 + lk);
      #pragma unroll
      for (int n = 0; n < 4; ++n)
        bfr[n] = *(const bf16x8*)(Bs + (wn*64 + n*16 + lr)*BK + kk*32 + lk);
      #pragma unroll
      for (int m = 0; m < 4; ++m)
        #pragma unroll
        for (int n = 0; n < 4; ++n)
          acc[m][n] = __builtin_amdgcn_mfma_f32_16x16x32_bf16(af[m], bfr[n], acc[m][n], 0, 0, 0);
    }
    __syncthreads();
  }

  const int orow0 = rt*BM + wm*64;
  const int ocol0 = ct*BN + wn*64;
  #pragma unroll
  for (int n = 0; n < 4; ++n) {
    float s = 0.f, qq = 0.f;
    #pragma unroll
    for (int m = 0; m < 4; ++m) {
      #pragma unroll
      for (int r = 0; r < 4; ++r) {
        float v = acc[m][n][r];
        int row = orow0 + m*16 + (l >> 4)*4 + r;
        int col = ocol0 + n*16 + lr;
        size_t off = (size_t)row * NTOT + col;
        if (OUTBF) Yb[off] = f2bf(v); else Yf[off] = v;
        s += v; qq += v*v;
      }
    }
    s  += __shfl_xor(s, 16);  s  += __shfl_xor(s, 32);
    qq += __shfl_xor(qq, 16); qq += __shfl_xor(qq, 32);
    if (l < 16) {
      sred[wm][wn*64 + n*16 + l][0] = s;
      sred[wm][wn*64 + n*16 + l][1] = qq;
    }
  }
  __syncthreads();
  if (tid < BN) {
    float S = sred[0][tid][0] + sred[1][tid][0];
    float Q = sred[0][tid][1] + sred[1][tid][1];
    part[((size_t)rt * NTOT + ct*BN + tid) * 2 + 0] = S;
    part[((size_t)rt * NTOT + ct*BN + tid) * 2 + 1] = Q;
  }
}

// ---------------- GEMM2 with BN+ReLU fused on the A operand ----------------
template<int K, int NTOT>
__global__ __launch_bounds__(256) void gemm_bnrelu_stats(
    const unsigned short* __restrict__ Yin,
    const float* __restrict__ ab,
    const unsigned short* __restrict__ Bw,
    unsigned short* __restrict__ Yb,
    float* __restrict__ part)
{
  constexpr int BM = 128, BN = 128, BK = 64;
  constexpr int NCT = NTOT / BN;
  __shared__ unsigned short As[BM*BK];
  __shared__ unsigned short Bs[BN*BK];
  __shared__ float sa[K], sb[K];
  __shared__ float sred[2][BN][2];

  const int tid = threadIdx.x;
  const int l   = tid & 63;
  const int w   = tid >> 6;
  const int wm  = w >> 1, wn = w & 1;
  const int rt  = blockIdx.x / NCT, ct = blockIdx.x % NCT;
  const int lr  = l & 15;
  const int lk  = (l >> 4) * 8;
  const int cc  = tid & 7;
  const int r0  = tid >> 3;

  sa[tid] = ab[tid*2];
  sb[tid] = ab[tid*2 + 1];

  const unsigned short* Arow = Yin + (size_t)rt * BM * K;
  const unsigned short* Brow = Bw  + (size_t)ct * BN * K;

  f32x4 acc[4][4] = {};
  __syncthreads();

  for (int k0 = 0; k0 < K; k0 += BK) {
    #pragma unroll
    for (int q = 0; q < 4; ++q) {
      int chunk = q * 256 + tid;
      int row = chunk >> 3, c8 = chunk & 7;
      unsigned ldsoff = (unsigned)(q * 256 + (tid & ~63)) * 16u;
      gload16(Brow + (size_t)row * K + k0 + c8 * 8, (char*)Bs + ldsoff);
    }
    float a_[8], b_[8];
    *(float4*)&a_[0] = *(const float4*)&sa[k0 + cc*8];
    *(float4*)&a_[4] = *(const float4*)&sa[k0 + cc*8 + 4];
    *(float4*)&b_[0] = *(const float4*)&sb[k0 + cc*8];
    *(float4*)&b_[4] = *(const float4*)&sb[k0 + cc*8 + 4];
    #pragma unroll
    for (int q = 0; q < 4; ++q) {
      int row = q*32 + r0;
      u16x8 v = *(const u16x8*)(Arow + (size_t)row * K + k0 + cc*8);
      u16x8 o;
      #pragma unroll
      for (int e = 0; e < 8; ++e) {
        float f = fmaxf(fmaf(bf2f((unsigned short)v[e]), a_[e], b_[e]), 0.f);
        o[e] = f2bf(f);
      }
      *(u16x8*)((char*)As + (unsigned)(q*256 + tid) * 16u) = o;
    }
    __syncthreads();
    #pragma unroll
    for (int kk = 0; kk < BK/32; ++kk) {
      bf16x8 af[4], bfr[4];
      #pragma unroll
      for (int m = 0; m < 4; ++m)
        af[m] = *(const bf16x8*)(As + (wm*64 + m*16 + lr)*BK + kk*32 + lk);
      #pragma unroll
      for (int n = 0; n < 4; ++n)
        bfr[n] = *(const bf16x8*)(Bs + (wn*64 + n*16 + lr)*BK + kk*32 + lk);
      #pragma unroll
      for (int m = 0; m < 4; ++m)
        #pragma unroll
        for (int n = 0; n < 4; ++n)
          acc[m][n] = __builtin_amdgcn_mfma_f32_16x16x32_bf16(af[m], bfr[n], acc[m][n], 0, 0, 0);
    }
    __syncthreads();
  }

  const int orow0 = rt*BM + wm*64;
  const int ocol0 = ct*BN + wn*64;
  #pragma unroll
  for (int n = 0; n < 4; ++n) {
    float s = 0.f, qq = 0.f;
    #pragma unroll
    for (int m = 0; m < 4; ++m) {
      #pragma unroll
      for (int r = 0; r < 4; ++r) {
        float v = acc[m][n][r];
        int row = orow0 + m*16 + (l >> 4)*4 + r;
        int col = ocol0 + n*16 + lr;
        Yb[(size_t)row * NTOT + col] = f2bf(v);
        s += v; qq += v*v;
      }
    }
    s  += __shfl_xor(s, 16);  s  += __shfl_xor(s, 32);
    qq += __shfl_xor(qq, 16); qq += __shfl_xor(qq, 32);
    if (l < 16) {
      sred[wm][wn*64 + n*16 + l][0] = s;
      sred[wm][wn*64 + n*16 + l][1] = qq;
    }
  }
  __syncthreads();
  if (tid < BN) {
    float S = sred[0][tid][0] + sred[1][tid][0];
    float Q = sred[0][tid][1] + sred[1][tid][1];
    part[((size_t)rt * NTOT + ct*BN + tid) * 2 + 0] = S;
    part[((size_t)rt * NTOT + ct*BN + tid) * 2 + 1] = Q;
  }
}

// ---------------- finalize: per-channel partials -> (a,b) BN coeffs -------
__global__ void finalize_stats(const float* __restrict__ part,
                               const float* __restrict__ g,
                               const float* __restrict__ be,
                               float* __restrict__ ab, int nrt, int C, float invM)
{
  const int c = blockIdx.x;
  const int t = threadIdx.x;
  float s = 0.f, q = 0.f;
  for (int r = t; r < nrt; r += 64) {
    s += part[((size_t)r * C + c) * 2 + 0];
    q += part[((size_t)r * C + c) * 2 + 1];
  }
  #pragma unroll
  for (int o = 32; o > 0; o >>= 1) { s += __shfl_down(s, o); q += __shfl_down(q, o); }
  if (t == 0) {
    float mean = s * invM;
    float var  = q * invM - mean * mean;
    float rstd = rsqrtf(var + 1e-5f);
    float a = g[c] * rstd;
    ab[c*2 + 0] = a;
    ab[c*2 + 1] = be[c] - mean * a;
  }
}

// ---------------- elementwise BN+ReLU (bf16 in -> fp32 out) ----------------
__global__ __launch_bounds__(256) void bnrelu_out(
    const unsigned short* __restrict__ Y, const float* __restrict__ ab,
    float* __restrict__ out)
{
  __shared__ float sa[H2_], sb[H2_];
  if (threadIdx.x < H2_) { sa[threadIdx.x] = ab[threadIdx.x*2]; sb[threadIdx.x] = ab[threadIdx.x*2+1]; }
  __syncthreads();
  const size_t total = (size_t)ROWS_ * H2_ / 8;
  for (size_t i = (size_t)blockIdx.x*256 + threadIdx.x; i < total; i += (size_t)gridDim.x*256) {
    u16x8 v = ((const u16x8*)Y)[i];
    int cb = (int)((i * 8) & (H2_ - 1));
    float4 o0, o1;
    o0.x = fmaxf(fmaf(bf2f((unsigned short)v[0]), sa[cb+0], sb[cb+0]), 0.f);
    o0.y = fmaxf(fmaf(bf2f((unsigned short)v[1]), sa[cb+1], sb[cb+1]), 0.f);
    o0.z = fmaxf(fmaf(bf2f((unsigned short)v[2]), sa[cb+2], sb[cb+2]), 0.f);
    o0.w = fmaxf(fmaf(bf2f((unsigned short)v[3]), sa[cb+3], sb[cb+3]), 0.f);
    o1.x = fmaxf(fmaf(bf2f((unsigned short)v[4]), sa[cb+4], sb[cb+4]), 0.f);
    o1.y = fmaxf(fmaf(bf2f((unsigned short)v[5]), sa[cb+5], sb[cb+5]), 0.f);
    o1.z = fmaxf(fmaf(bf2f((unsigned short)v[6]), sa[cb+6], sb[cb+6]), 0.f);
    o1.w = fmaxf(fmaf(bf2f((unsigned short)v[7]), sa[cb+7], sb[cb+7]), 0.f);
    ((float4*)out)[i*2]   = o0;
    ((float4*)out)[i*2+1] = o1;
  }
}

// ---------------- launch -------------------------------------------------
extern "C" void kernel_launch(void* const* d_in, const int* in_sizes, int n_in,
                              void* d_out, int out_size, void* d_ws, size_t ws_size,
                              hipStream_t stream)
{
  const float* xyzf = (const float*)d_in[0];
  const float* xyzc = (const float*)d_in[1];
  const float* ff   = (const float*)d_in[2];
  const float* fc   = (const float*)d_in[3];
  const float* W1   = (const float*)d_in[4];
  const float* g1   = (const float*)d_in[6];
  const float* be1  = (const float*)d_in[7];
  const float* W2   = (const float*)d_in[8];
  const float* g2   = (const float*)d_in[10];
  const float* be2  = (const float*)d_in[11];
  float* out = (float*)d_out;

  char* ws = (char*)d_ws;
  // layout (bytes), 256-aligned. Lifetime aliasing as before.
  unsigned short* W1b  = (unsigned short*)(ws + 0);          // 163840
  unsigned short* W2b  = (unsigned short*)(ws + 163840);     // 65536
  unsigned short* X    = (unsigned short*)(ws + 229376);     // 41943040
  unsigned short* Y2b  = (unsigned short*)(ws + 229376);     // 16777216 (alias X)
  unsigned short* fcb  = (unsigned short*)(ws + 42172416);   // 8388608
  unsigned short* Y1   = (unsigned short*)(ws + 42172416);   // 33554432 (alias fcb)
  float* part1 = (float*)(ws + 75726848);                    // 1048576
  float* part2 = (float*)(ws + 76775424);                    // 524288
  float* ab1   = (float*)(ws + 77299712);                    // 2048
  float* ab2   = (float*)(ws + 77301760);                    // 1024
  float4* cpk  = (float4*)(ws + 77302784);                   // 262144
  float4* pdw  = (float4*)(ws + 77564928);                   // 1048576 (SPLIT=1)
  int4*   piw  = (int4*)  (ws + 85953536);                   // 1048576
  float4* cps  = (float4*)(ws + 88051712);                   // 262144
  float*  sxs  = (float*) (ws + 88313856);                   // 65536
  int*    lov  = (int*)   (ws + 88379392);                   // 262144
  int*    hist = (int*)   (ws + 88641536);                   // 66560
  int*    offs = (int*)   (ws + 88708096);                   // 66560
  unsigned* perm = (unsigned*)(ws + 88774656);               // 262144 (end ~89MB)

  prep<<<1024, 256, 0, stream>>>(W1, W2, xyzc, fc, W1b, W2b, cpk, fcb);
  sort_coarse<<<B_, 1024, 0, stream>>>(cpk, sxs, cps);
  hipMemsetAsync(hist, 0, B_ * NBIN_ * sizeof(int), stream);
  lo_hist<<<B_ * 64, 256, 0, stream>>>(xyzf, sxs, lov, hist);
  prefix_bins<<<B_, 64, 0, stream>>>(hist, offs);
  scatter_perm<<<B_ * 64, 256, 0, stream>>>(lov, offs, perm);
  nn_bucket<<<B_ * 64, 256, 0, stream>>>(xyzf, cps, perm, pdw, piw);
  nn_finish<<<B_ * 256, 256, 0, stream>>>(pdw, piw, ff, fcb, X);

  // layer 1: y1 = X @ W1^T  (M=65536, N=256, K=320), stats fused
  gemm_stats<CIN_, H1_, true><<<(ROWS_/128) * (H1_/128), 256, 0, stream>>>(
      X, W1b, Y1, nullptr, part1);
  finalize_stats<<<H1_, 64, 0, stream>>>(part1, g1, be1, ab1, ROWS_/128, H1_, 1.f/ROWS_);

  // layer 2: y2 = relu(bn1(Y1)) @ W2^T with BN+ReLU fused into the A-load
  gemm_bnrelu_stats<H1_, H2_><<<(ROWS_/128) * (H2_/128), 256, 0, stream>>>(
      Y1, ab1, W2b, Y2b, part2);
  finalize_stats<<<H2_, 64, 0, stream>>>(part2, g2, be2, ab2, ROWS_/128, H2_, 1.f/ROWS_);
  bnrelu_out<<<2048, 256, 0, stream>>>(Y2b, ab2, out);
}

// Round 18
// 420.923 us; speedup vs baseline: 1.4308x; 1.4308x over previous
//
#include <hip/hip_runtime.h>
#include <hip/hip_bf16.h>
#include <stdint.h>

// Problem dims (fixed by setup_inputs)
#define B_    4
#define N_    16384
#define M_    4096
#define C1_   64
#define C2_   256
#define CIN_  320   // C2 + C1 (concat order: [interp(256), fine(64)])
#define H1_   256
#define H2_   128
#define ROWS_ (B_*N_)   // 65536
#define SPLIT_ 1
#define NBIN_ 4160      // 4097 lo-bins (0..4096), padded
#define W_    512       // half-window (index units) per point
#define WCH_  256       // per-thread chunk = 2*W_/4
#define SLAB_ 1536      // LDS slab (float4 entries)

typedef __attribute__((ext_vector_type(8))) short bf16x8;
typedef __attribute__((ext_vector_type(4))) float f32x4;
typedef __attribute__((ext_vector_type(8))) unsigned short u16x8;
typedef __attribute__((ext_vector_type(4))) unsigned short u16x4;

static __device__ __forceinline__ unsigned short f2bf(float f) {
  union { float f; unsigned u; } v; v.f = f;
  unsigned r = v.u + 0x7fffu + ((v.u >> 16) & 1u);
  return (unsigned short)(r >> 16);
}
static __device__ __forceinline__ float bf2f(unsigned short h) {
  union { unsigned u; float f; } v; v.u = ((unsigned)h) << 16;
  return v.f;
}

// async global->LDS, 16B per lane. lds base must be wave-uniform.
static __device__ __forceinline__ void gload16(const void* g, void* lds) {
  __builtin_amdgcn_global_load_lds(
      (__attribute__((address_space(1))) void*)(uintptr_t)g,
      (__attribute__((address_space(3))) void*)(uintptr_t)lds,
      16, 0, 0);
}

// strict-< top-3 insert (merge): ties keep the earlier entry.
#define INS3(dv, iv) do {                                        \
  float _d = (dv); int _ii = (iv);                               \
  if (_d < d3) {                                                 \
    if (_d < d2) {                                               \
      d3 = d2; i3 = i2;                                          \
      if (_d < d1) { d2 = d1; i2 = i1; d1 = _d; i1 = _ii; }      \
      else         { d2 = _d; i2 = _ii; }                        \
    } else { d3 = _d; i3 = _ii; }                                \
  } } while (0)

// flat strict-< insert into (D1<=D2<=D3)/(I1,I2,I3) -- R10-validated form.
#define FLAT3(d, idx) do {                                       \
  if ((d) < D3) {                                                \
    bool c1 = (d) < D1, c2 = (d) < D2;                           \
    D3 = c2 ? D2 : (d);            I3 = c2 ? I2 : (idx);         \
    D2 = c1 ? D1 : (c2 ? (d) : D2); I2 = c1 ? I1 : (c2 ? (idx) : I2); \
    D1 = c1 ? (d) : D1;            I1 = c1 ? (idx) : I1;         \
  } } while (0)

// ---------------- kernel 0: weights + coarse feats -> bf16, pts -> float4 --
__global__ __launch_bounds__(256) void prep(
    const float* __restrict__ W1, const float* __restrict__ W2,
    const float* __restrict__ xyzc, const float* __restrict__ fc,
    unsigned short* __restrict__ W1b, unsigned short* __restrict__ W2b,
    float4* __restrict__ cpk, unsigned short* __restrict__ fcb)
{
  int i = blockIdx.x * 256 + threadIdx.x;
  if (i < H1_*CIN_) W1b[i] = f2bf(W1[i]);
  if (i < H2_*H1_)  W2b[i] = f2bf(W2[i]);
  if (i < B_*M_) {
    float x = xyzc[i*3], y = xyzc[i*3+1], z = xyzc[i*3+2];
    cpk[i] = make_float4(x, y, z, x*x + y*y + z*z);
  }
  const int total4 = B_*M_*C2_/4;
  const int stride = gridDim.x * 256;
  for (int t = i; t < total4; t += stride) {
    float4 v = ((const float4*)fc)[t];
    u16x4 o;
    o[0] = f2bf(v.x); o[1] = f2bf(v.y); o[2] = f2bf(v.z); o[3] = f2bf(v.w);
    ((u16x4*)fcb)[t] = o;
  }
}

// ---------------- kernel 1: bitonic sort coarse points by x (validated) ----
__global__ __launch_bounds__(1024) void sort_coarse(
    const float4* __restrict__ cpk,
    float* __restrict__ sxs, float4* __restrict__ cps)
{
  __shared__ unsigned long long key[M_];
  const int b = blockIdx.x;
  const int tid = threadIdx.x;
  for (int i = tid; i < M_; i += 1024) {
    unsigned ux = __float_as_uint(cpk[(size_t)b*M_ + i].x);
    ux ^= (ux >> 31) ? 0xFFFFFFFFu : 0x80000000u;   // monotone float->u32
    key[i] = ((unsigned long long)ux << 32) | (unsigned)i;
  }
  __syncthreads();
  for (int k = 2; k <= M_; k <<= 1) {
    for (int j = k >> 1; j > 0; j >>= 1) {
      for (int i = tid; i < M_; i += 1024) {
        int ixj = i ^ j;
        if (ixj > i) {
          unsigned long long a = key[i], c = key[ixj];
          bool up = ((i & k) == 0);
          if ((a > c) == up) { key[i] = c; key[ixj] = a; }
        }
      }
      __syncthreads();
    }
  }
  for (int i = tid; i < M_; i += 1024) {
    int idx = (int)(unsigned)key[i];            // low 32 bits
    float4 c = cpk[(size_t)b*M_ + idx];
    sxs[(size_t)b*M_ + i] = c.x;
    cps[(size_t)b*M_ + i] = make_float4(c.x, c.y, c.z, __int_as_float(idx));
  }
}

// ---------------- kernel 2a: per-fine-point lo (binary search) + histogram -
__global__ __launch_bounds__(256) void lo_hist(
    const float* __restrict__ xyzf, const float* __restrict__ sxs,
    int* __restrict__ lov, int* __restrict__ hist)
{
  __shared__ float sx_l[M_];
  const int tid  = threadIdx.x;
  const int tile = blockIdx.x & 63;
  const int b    = blockIdx.x >> 6;
  const float4* srcx = (const float4*)(sxs + (size_t)b * M_);
  for (int i = tid; i < M_/4; i += 256) ((float4*)sx_l)[i] = srcx[i];
  __syncthreads();
  const int p = tile * 256 + tid;
  const size_t gp = (size_t)b * N_ + p;
  const float px = xyzf[gp * 3];
  int lo = 0, hi = M_;
  while (lo < hi) { int mid = (lo + hi) >> 1; if (sx_l[mid] < px) lo = mid + 1; else hi = mid; }
  lov[gp] = lo;
  atomicAdd(&hist[b * NBIN_ + lo], 1);
}

// ---------------- kernel 2b: exclusive prefix over 4097 bins (1 wave/batch)
__global__ __launch_bounds__(64) void prefix_bins(
    const int* __restrict__ hist, int* __restrict__ offs)
{
  const int b = blockIdx.x, t = threadIdx.x;
  const int PER = 65;                    // 64*65 = 4160 covers 0..4096
  int s = 0;
  for (int k = 0; k < PER; ++k) {
    int idx = t * PER + k;
    s += (idx <= M_) ? hist[b * NBIN_ + idx] : 0;
  }
  int incl = s;
  #pragma unroll
  for (int o = 1; o < 64; o <<= 1) {
    int v = __shfl_up(incl, o);
    if (t >= o) incl += v;
  }
  int run = incl - s;
  for (int k = 0; k < PER; ++k) {
    int idx = t * PER + k;
    if (idx <= M_) {
      int h = hist[b * NBIN_ + idx];
      offs[b * NBIN_ + idx] = run;
      run += h;
    }
  }
}

// ---------------- kernel 2c: scatter -> perm (lo-sorted fine point list) ---
__global__ __launch_bounds__(256) void scatter_perm(
    const int* __restrict__ lov, int* __restrict__ offs,
    unsigned* __restrict__ perm)
{
  const int tid  = threadIdx.x;
  const int tile = blockIdx.x & 63;
  const int b    = blockIdx.x >> 6;
  const int p    = tile * 256 + tid;
  const size_t gp = (size_t)b * N_ + p;
  int lo = lov[gp];
  int pos = atomicAdd(&offs[b * NBIN_ + lo], 1);
  perm[(size_t)b * N_ + pos] = ((unsigned)p << 13) | (unsigned)lo;
}

// ---------------- kernel 3: 3-NN via FIXED window [lo-512, lo+512) ---------
// grid: B*256 blocks (1024) x 256 thr (4 waves, 16 waves/CU). Each block owns
// 64 lo-sorted points; each point is scanned by 4 threads (contiguous
// 256-candidate chunks, merged in chunk order = x-ascending => same strict-<
// semantics as the validated single scan). NO ballot / NO adaptive exit (R17
// failure: wave-max coupling at 1 wave/SIMD). Candidates come from a 24KB
// LDS slab [jl0, jl0+1536); chunk parts outside slab (block-boundary or
// freak lo-range) fall back to per-candidate global reads. Exactness: a
// conservative per-point safety check (window-edge dx^2 >= D3; <3 found =>
// unsafe) flags points whose true 3NN might lie outside the fixed window;
// those are re-done exactly by nn_brute_flag. Output is deterministic:
// windows depend only on (point, lo), not on perm grouping.
__global__ __launch_bounds__(256) void nn_window(
    const float* __restrict__ xyzf, const float4* __restrict__ cps,
    const unsigned* __restrict__ perm,
    float4* __restrict__ pdw, int4* __restrict__ piw,
    int* __restrict__ flagcnt, int* __restrict__ flaglist)
{
  __shared__ float4 cl[SLAB_];
  __shared__ float  md[4][64][3];
  __shared__ int    mi[4][64][3];
  const int tid  = threadIdx.x;
  const int blk  = blockIdx.x & 255;
  const int b    = blockIdx.x >> 8;
  const int lane = tid & 63;             // point slot in block
  const int q    = tid >> 6;             // chunk quarter
  const unsigned* pb = perm + (size_t)b * N_ + blk * 64;
  const float4* cpsb = cps + (size_t)b * M_;

  const int lo_first = (int)(pb[0] & 8191u);
  const int jl0   = max(0, lo_first - W_);
  const int slend = min(M_, jl0 + SLAB_);   // slab covers [jl0, slend)
  for (int i = tid; i < slend - jl0; i += 256) cl[i] = cpsb[jl0 + i];
  __syncthreads();

  const unsigned e = pb[lane];
  const int ip = (int)(e >> 13);
  const int lo = (int)(e & 8191u);
  const size_t gp = (size_t)b * N_ + ip;
  const float px = xyzf[gp*3], py = xyzf[gp*3+1], pz = xyzf[gp*3+2];

  float D1 = 3.4e38f, D2 = 3.4e38f, D3 = 3.4e38f;
  int   I1 = 0, I2 = 0, I3 = 0;
  const int c0 = lo - W_ + q * WCH_;      // this thread's chunk start

  if (c0 >= jl0 && c0 + WCH_ <= slend) {
    // common path: whole chunk in slab, unguarded dense loop
    const int o0 = c0 - jl0;
    #pragma unroll 4
    for (int t = 0; t < WCH_; ++t) {
      float4 c = cl[o0 + t];
      float ax = c.x - px, ay = c.y - py, az = c.z - pz;
      float d = fmaf(ax, ax, fmaf(ay, ay, az * az));
      int idx = __float_as_int(c.w);
      FLAT3(d, idx);
    }
  } else {
    // boundary path: per-candidate validity + slab/global select
    #pragma unroll 2
    for (int t = 0; t < WCH_; ++t) {
      int j = c0 + t;
      bool valid = (j >= 0) && (j < M_);
      float4 c;
      if (valid && j >= jl0 && j < slend) c = cl[j - jl0];
      else if (valid)                     c = cpsb[j];
      else                                c = make_float4(3.4e38f, 3.4e38f, 3.4e38f, 0.f);
      float ax = c.x - px, ay = c.y - py, az = c.z - pz;
      float d = fmaf(ax, ax, fmaf(ay, ay, az * az));
      int idx = __float_as_int(c.w);
      if (valid) FLAT3(d, idx);
    }
  }

  md[q][lane][0] = D1; md[q][lane][1] = D2; md[q][lane][2] = D3;
  mi[q][lane][0] = I1; mi[q][lane][1] = I2; mi[q][lane][2] = I3;
  __syncthreads();

  if (tid < 64) {
    float d1 = 3.4e38f, d2 = 3.4e38f, d3 = 3.4e38f;
    int   i1 = 0, i2 = 0, i3 = 0;
    #pragma unroll
    for (int s = 0; s < 4; ++s) {        // chunk order = x-ascending
      INS3(md[s][tid][0], mi[s][tid][0]);
      INS3(md[s][tid][1], mi[s][tid][1]);
      INS3(md[s][tid][2], mi[s][tid][2]);
    }
    const unsigned e2 = pb[tid];
    const int ip2 = (int)(e2 >> 13);
    const int lo2 = (int)(e2 & 8191u);
    const size_t gp2 = (size_t)b * N_ + ip2;
    const float px2 = xyzf[gp2*3];
    // safety: unscanned left has x <= x[jls] (jls scanned, x[jls] < px2 since
    // jls < lo2); unscanned right starts at jrs with x >= x[jrs] >= px2.
    // d_unscanned >= dx^2 >= d3 => cannot beat strict-< top-3. d3==inf
    // (<3 found) fails the check => flagged. Conservative, exact.
    const int jls = lo2 - W_;
    const int jrs = lo2 + W_;
    bool safeL = (jls <= 0);
    if (!safeL) {
      float xl = (jls >= jl0 && jls < slend) ? cl[jls - jl0].x : cpsb[jls].x;
      float dx = px2 - xl;
      safeL = (dx * dx >= d3);
    }
    bool safeR = (jrs >= M_);
    if (!safeR) {
      float xr = (jrs >= jl0 && jrs < slend) ? cl[jrs - jl0].x : cpsb[jrs].x;
      float dx = xr - px2;
      safeR = (dx * dx >= d3);
    }
    if (safeL && safeR) {
      pdw[gp2] = make_float4(d1, d2, d3, 0.f);
      piw[gp2] = make_int4(i1, i2, i3, 0);
    } else {
      int pos = atomicAdd(flagcnt, 1);
      flaglist[pos] = (int)gp2;          // capacity ROWS_: cannot overflow
    }
  }
}

// ---------------- kernel 3b: exact brute-force for flagged points ----------
// grid-stride over flagcnt; 1 wave per flagged point. Lane l scans ORIGINAL
// indices [64l, 64l+64) (exact ascending), lane partials merged in lane
// order => bit-exact jax top_k tie semantics. Uses the R13-validated
// distance formula. Writes overwrite pdw/piw before nn_finish runs.
__global__ __launch_bounds__(64) void nn_brute_flag(
    const float* __restrict__ xyzf, const float4* __restrict__ cpk,
    const int* __restrict__ flagcnt, const int* __restrict__ flaglist,
    float4* __restrict__ pdw, int4* __restrict__ piw)
{
  __shared__ float ld[64][3];
  __shared__ int   li[64][3];
  const int nf = *flagcnt;
  for (int fi = blockIdx.x; fi < nf; fi += gridDim.x) {
    const int gp = flaglist[fi];
    const int b  = gp >> 14;             // N_ = 16384
    const float* xf = xyzf + (size_t)gp * 3;
    const float fx = xf[0], fy = xf[1], fz = xf[2];
    const float xx = fx*fx + fy*fy + fz*fz;
    const float nx = -2.f*fx, ny = -2.f*fy, nz = -2.f*fz;
    const float4* cb = cpk + (size_t)b * M_;
    float D1 = 3.4e38f, D2 = 3.4e38f, D3 = 3.4e38f;
    int   I1 = 0, I2 = 0, I3 = 0;
    const int j0 = threadIdx.x * 64;
    for (int t = 0; t < 64; ++t) {
      int j = j0 + t;
      float4 c = cb[j];
      float d = xx + fmaf(nx, c.x, fmaf(ny, c.y, fmaf(nz, c.z, c.w)));
      FLAT3(d, j);
    }
    ld[threadIdx.x][0] = D1; ld[threadIdx.x][1] = D2; ld[threadIdx.x][2] = D3;
    li[threadIdx.x][0] = I1; li[threadIdx.x][1] = I2; li[threadIdx.x][2] = I3;
    __syncthreads();
    if (threadIdx.x == 0) {
      float d1 = 3.4e38f, d2 = 3.4e38f, d3 = 3.4e38f;
      int   i1 = 0, i2 = 0, i3 = 0;
      for (int l = 0; l < 64; ++l) {     // lane order = index-ascending
        INS3(ld[l][0], li[l][0]);
        INS3(ld[l][1], li[l][1]);
        INS3(ld[l][2], li[l][2]);
      }
      pdw[gp] = make_float4(d1, d2, d3, 0.f);
      piw[gp] = make_int4(i1, i2, i3, 0);
    }
    __syncthreads();
  }
}

// ---------------- kernel 4: merge(single) + weights + interp + concat ------
__global__ __launch_bounds__(256) void nn_finish(
    const float4* __restrict__ pdw, const int4* __restrict__ piw,
    const float* __restrict__ ff, const unsigned short* __restrict__ fcb,
    unsigned short* __restrict__ X)
{
  __shared__ float wv[64][3];
  __shared__ int   wi[64][3];
  const int tid  = threadIdx.x;
  const int b    = blockIdx.x >> 8;
  const int tile = blockIdx.x & 255;
  const size_t gp0 = (size_t)b * N_ + tile * 64;

  if (tid < 64) {
    const size_t gp = gp0 + tid;
    float d1 = 3.4e38f, d2 = 3.4e38f, d3 = 3.4e38f;
    int   i1 = 0, i2 = 0, i3 = 0;
    #pragma unroll
    for (int s = 0; s < SPLIT_; ++s) {
      float4 dv = pdw[(size_t)s * ROWS_ + gp];
      int4   iv = piw[(size_t)s * ROWS_ + gp];
      INS3(dv.x, iv.x);
      INS3(dv.y, iv.y);
      INS3(dv.z, iv.z);
    }
    d1 = fmaxf(d1, 1e-10f); d2 = fmaxf(d2, 1e-10f); d3 = fmaxf(d3, 1e-10f);
    float u1 = 1.f/d1, u2 = 1.f/d2, u3 = 1.f/d3;
    float inv = 1.f/(u1 + u2 + u3);
    wv[tid][0] = u1*inv; wv[tid][1] = u2*inv; wv[tid][2] = u3*inv;
    wi[tid][0] = i1;     wi[tid][1] = i2;     wi[tid][2] = i3;
  }
  __syncthreads();

  const int w = tid >> 6, l = tid & 63;
  const unsigned short* fcb_b = fcb + (size_t)b * M_ * C2_;
  unsigned short* Xb = X + gp0 * CIN_;
  #pragma unroll 2
  for (int q = 0; q < 16; ++q) {
    int pl = w * 16 + q;
    float a1 = wv[pl][0], a2 = wv[pl][1], a3 = wv[pl][2];
    int   j1 = wi[pl][0], j2 = wi[pl][1], j3 = wi[pl][2];
    u16x4 r1 = ((const u16x4*)(fcb_b + (size_t)j1 * C2_))[l];
    u16x4 r2 = ((const u16x4*)(fcb_b + (size_t)j2 * C2_))[l];
    u16x4 r3 = ((const u16x4*)(fcb_b + (size_t)j3 * C2_))[l];
    u16x4 o;
    #pragma unroll
    for (int e = 0; e < 4; ++e) {
      float v = fmaf(a1, bf2f(r1[e]), fmaf(a2, bf2f(r2[e]), a3 * bf2f(r3[e])));
      o[e] = f2bf(v);
    }
    *(u16x4*)(Xb + (size_t)pl * CIN_ + l * 4) = o;
  }

  {
    const float* ffb = ff + gp0 * C1_;
    int pl = tid >> 2, c0 = (tid & 3) * 16;
    const float4* fsrc = (const float4*)(ffb + (size_t)pl * C1_ + c0);
    unsigned short* dst = Xb + (size_t)pl * CIN_ + C2_ + c0;
    #pragma unroll
    for (int t = 0; t < 4; ++t) {
      float4 v = fsrc[t];
      u16x4 o;
      o[0] = f2bf(v.x); o[1] = f2bf(v.y); o[2] = f2bf(v.z); o[3] = f2bf(v.w);
      *(u16x4*)(dst + t * 4) = o;
    }
  }
}

// ---------------- GEMM: C[M][NTOT] = A[M][K] * Bw[NTOT][K]^T + col stats ---
template<int K, int NTOT, bool OUTBF>
__global__ __launch_bounds__(256) void gemm_stats(
    const unsigned short* __restrict__ A,
    const unsigned short* __restrict__ Bw,
    unsigned short* __restrict__ Yb,
    float* __restrict__ Yf,
    float* __restrict__ part)
{
  constexpr int BM = 128, BN = 128, BK = 64;
  constexpr int NCT = NTOT / BN;
  __shared__ unsigned short As[BM*BK];
  __shared__ unsigned short Bs[BN*BK];
  __shared__ float sred[2][BN][2];

  const int tid = threadIdx.x;
  const int l   = tid & 63;
  const int w   = tid >> 6;
  const int wm  = w >> 1, wn = w & 1;
  int rt, ct;
  if (NCT == 2) {
    rt = (blockIdx.x & 7) | ((blockIdx.x >> 4) << 3);
    ct = (blockIdx.x >> 3) & 1;
  } else {
    rt = blockIdx.x / NCT; ct = blockIdx.x % NCT;
  }
  const int lr  = l & 15;
  const int lk  = (l >> 4) * 8;

  const unsigned short* Arow = A  + (size_t)rt * BM * K;
  const unsigned short* Brow = Bw + (size_t)ct * BN * K;

  f32x4 acc[4][4] = {};

  for (int k0 = 0; k0 < K; k0 += BK) {
    #pragma unroll
    for (int q = 0; q < 4; ++q) {
      int chunk = q * 256 + tid;
      int row = chunk >> 3, cc = chunk & 7;
      unsigned ldsoff = (unsigned)(q * 256 + (tid & ~63)) * 16u;   // wave-uniform
      gload16(Arow + (size_t)row * K + k0 + cc * 8, (char*)As + ldsoff);
      gload16(Brow + (size_t)row * K + k0 + cc * 8, (char*)Bs + ldsoff);
    }
    __syncthreads();
    #pragma unroll
    for (int kk = 0; kk < BK/32; ++kk) {
      bf16x8 af[4], bfr[4];
      #pragma unroll
      for (int m = 0; m < 4; ++m)
        af[m] = *(const bf16x8*)(As + (wm*64 + m*16 + lr)*BK + kk*32 + lk);
      #pragma unroll
      for (int n = 0; n < 4; ++n)
        bfr[n] = *(const bf16x8*)(Bs + (wn*64 + n*16 + lr)*BK + kk*32 + lk);
      #pragma unroll
      for (int m = 0; m < 4; ++m)
        #pragma unroll
        for (int n = 0; n < 4; ++n)
          acc[m][n] = __builtin_amdgcn_mfma_f32_16x16x32_bf16(af[m], bfr[n], acc[m][n], 0, 0, 0);
    }
    __syncthreads();
  }

  const int orow0 = rt*BM + wm*64;
  const int ocol0 = ct*BN + wn*64;
  #pragma unroll
  for (int n = 0; n < 4; ++n) {
    float s = 0.f, qq = 0.f;
    #pragma unroll
    for (int m = 0; m < 4; ++m) {
      #pragma unroll
      for (int r = 0; r < 4; ++r) {
        float v = acc[m][n][r];
        int row = orow0 + m*16 + (l >> 4)*4 + r;
        int col = ocol0 + n*16 + lr;
        size_t off = (size_t)row * NTOT + col;
        if (OUTBF) Yb[off] = f2bf(v); else Yf[off] = v;
        s += v; qq += v*v;
      }
    }
    s  += __shfl_xor(s, 16);  s  += __shfl_xor(s, 32);
    qq += __shfl_xor(qq, 16); qq += __shfl_xor(qq, 32);
    if (l < 16) {
      sred[wm][wn*64 + n*16 + l][0] = s;
      sred[wm][wn*64 + n*16 + l][1] = qq;
    }
  }
  __syncthreads();
  if (tid < BN) {
    float S = sred[0][tid][0] + sred[1][tid][0];
    float Q = sred[0][tid][1] + sred[1][tid][1];
    part[((size_t)rt * NTOT + ct*BN + tid) * 2 + 0] = S;
    part[((size_t)rt * NTOT + ct*BN + tid) * 2 + 1] = Q;
  }
}

// ---------------- GEMM2 with BN+ReLU fused on the A operand ----------------
template<int K, int NTOT>
__global__ __launch_bounds__(256) void gemm_bnrelu_stats(
    const unsigned short* __restrict__ Yin,
    const float* __restrict__ ab,
    const unsigned short* __restrict__ Bw,
    unsigned short* __restrict__ Yb,
    float* __restrict__ part)
{
  constexpr int BM = 128, BN = 128, BK = 64;
  constexpr int NCT = NTOT / BN;
  __shared__ unsigned short As[BM*BK];
  __shared__ unsigned short Bs[BN*BK];
  __shared__ float sa[K], sb[K];
  __shared__ float sred[2][BN][2];

  const int tid = threadIdx.x;
  const int l   = tid & 63;
  const int w   = tid >> 6;
  const int wm  = w >> 1, wn = w & 1;
  const int rt  = blockIdx.x / NCT, ct = blockIdx.x % NCT;
  const int lr  = l & 15;
  const int lk  = (l >> 4) * 8;
  const int cc  = tid & 7;
  const int r0  = tid >> 3;

  sa[tid] = ab[tid*2];
  sb[tid] = ab[tid*2 + 1];

  const unsigned short* Arow = Yin + (size_t)rt * BM * K;
  const unsigned short* Brow = Bw  + (size_t)ct * BN * K;

  f32x4 acc[4][4] = {};
  __syncthreads();

  for (int k0 = 0; k0 < K; k0 += BK) {
    #pragma unroll
    for (int q = 0; q < 4; ++q) {
      int chunk = q * 256 + tid;
      int row = chunk >> 3, c8 = chunk & 7;
      unsigned ldsoff = (unsigned)(q * 256 + (tid & ~63)) * 16u;
      gload16(Brow + (size_t)row * K + k0 + c8 * 8, (char*)Bs + ldsoff);
    }
    float a_[8], b_[8];
    *(float4*)&a_[0] = *(const float4*)&sa[k0 + cc*8];
    *(float4*)&a_[4] = *(const float4*)&sa[k0 + cc*8 + 4];
    *(float4*)&b_[0] = *(const float4*)&sb[k0 + cc*8];
    *(float4*)&b_[4] = *(const float4*)&sb[k0 + cc*8 + 4];
    #pragma unroll
    for (int q = 0; q < 4; ++q) {
      int row = q*32 + r0;
      u16x8 v = *(const u16x8*)(Arow + (size_t)row * K + k0 + cc*8);
      u16x8 o;
      #pragma unroll
      for (int e = 0; e < 8; ++e) {
        float f = fmaxf(fmaf(bf2f((unsigned short)v[e]), a_[e], b_[e]), 0.f);
        o[e] = f2bf(f);
      }
      *(u16x8*)((char*)As + (unsigned)(q*256 + tid) * 16u) = o;
    }
    __syncthreads();
    #pragma unroll
    for (int kk = 0; kk < BK/32; ++kk) {
      bf16x8 af[4], bfr[4];
      #pragma unroll
      for (int m = 0; m < 4; ++m)
        af[m] = *(const bf16x8*)(As + (wm*64 + m*16 + lr)*BK + kk*32 + lk);
      #pragma unroll
      for (int n = 0; n < 4; ++n)
        bfr[n] = *(const bf16x8*)(Bs + (wn*64 + n*16 + lr)*BK + kk*32 + lk);
      #pragma unroll
      for (int m = 0; m < 4; ++m)
        #pragma unroll
        for (int n = 0; n < 4; ++n)
          acc[m][n] = __builtin_amdgcn_mfma_f32_16x16x32_bf16(af[m], bfr[n], acc[m][n], 0, 0, 0);
    }
    __syncthreads();
  }

  const int orow0 = rt*BM + wm*64;
  const int ocol0 = ct*BN + wn*64;
  #pragma unroll
  for (int n = 0; n < 4; ++n) {
    float s = 0.f, qq = 0.f;
    #pragma unroll
    for (int m = 0; m < 4; ++m) {
      #pragma unroll
      for (int r = 0; r < 4; ++r) {
        float v = acc[m][n][r];
        int row = orow0 + m*16 + (l >> 4)*4 + r;
        int col = ocol0 + n*16 + lr;
        Yb[(size_t)row * NTOT + col] = f2bf(v);
        s += v; qq += v*v;
      }
    }
    s  += __shfl_xor(s, 16);  s  += __shfl_xor(s, 32);
    qq += __shfl_xor(qq, 16); qq += __shfl_xor(qq, 32);
    if (l < 16) {
      sred[wm][wn*64 + n*16 + l][0] = s;
      sred[wm][wn*64 + n*16 + l][1] = qq;
    }
  }
  __syncthreads();
  if (tid < BN) {
    float S = sred[0][tid][0] + sred[1][tid][0];
    float Q = sred[0][tid][1] + sred[1][tid][1];
    part[((size_t)rt * NTOT + ct*BN + tid) * 2 + 0] = S;
    part[((size_t)rt * NTOT + ct*BN + tid) * 2 + 1] = Q;
  }
}

// ---------------- finalize: per-channel partials -> (a,b) BN coeffs -------
__global__ void finalize_stats(const float* __restrict__ part,
                               const float* __restrict__ g,
                               const float* __restrict__ be,
                               float* __restrict__ ab, int nrt, int C, float invM)
{
  const int c = blockIdx.x;
  const int t = threadIdx.x;
  float s = 0.f, q = 0.f;
  for (int r = t; r < nrt; r += 64) {
    s += part[((size_t)r * C + c) * 2 + 0];
    q += part[((size_t)r * C + c) * 2 + 1];
  }
  #pragma unroll
  for (int o = 32; o > 0; o >>= 1) { s += __shfl_down(s, o); q += __shfl_down(q, o); }
  if (t == 0) {
    float mean = s * invM;
    float var  = q * invM - mean * mean;
    float rstd = rsqrtf(var + 1e-5f);
    float a = g[c] * rstd;
    ab[c*2 + 0] = a;
    ab[c*2 + 1] = be[c] - mean * a;
  }
}

// ---------------- elementwise BN+ReLU (bf16 in -> fp32 out) ----------------
__global__ __launch_bounds__(256) void bnrelu_out(
    const unsigned short* __restrict__ Y, const float* __restrict__ ab,
    float* __restrict__ out)
{
  __shared__ float sa[H2_], sb[H2_];
  if (threadIdx.x < H2_) { sa[threadIdx.x] = ab[threadIdx.x*2]; sb[threadIdx.x] = ab[threadIdx.x*2+1]; }
  __syncthreads();
  const size_t total = (size_t)ROWS_ * H2_ / 8;
  for (size_t i = (size_t)blockIdx.x*256 + threadIdx.x; i < total; i += (size_t)gridDim.x*256) {
    u16x8 v = ((const u16x8*)Y)[i];
    int cb = (int)((i * 8) & (H2_ - 1));
    float4 o0, o1;
    o0.x = fmaxf(fmaf(bf2f((unsigned short)v[0]), sa[cb+0], sb[cb+0]), 0.f);
    o0.y = fmaxf(fmaf(bf2f((unsigned short)v[1]), sa[cb+1], sb[cb+1]), 0.f);
    o0.z = fmaxf(fmaf(bf2f((unsigned short)v[2]), sa[cb+2], sb[cb+2]), 0.f);
    o0.w = fmaxf(fmaf(bf2f((unsigned short)v[3]), sa[cb+3], sb[cb+3]), 0.f);
    o1.x = fmaxf(fmaf(bf2f((unsigned short)v[4]), sa[cb+4], sb[cb+4]), 0.f);
    o1.y = fmaxf(fmaf(bf2f((unsigned short)v[5]), sa[cb+5], sb[cb+5]), 0.f);
    o1.z = fmaxf(fmaf(bf2f((unsigned short)v[6]), sa[cb+6], sb[cb+6]), 0.f);
    o1.w = fmaxf(fmaf(bf2f((unsigned short)v[7]), sa[cb+7], sb[cb+7]), 0.f);
    ((float4*)out)[i*2]   = o0;
    ((float4*)out)[i*2+1] = o1;
  }
}

// ---------------- launch -------------------------------------------------
extern "C" void kernel_launch(void* const* d_in, const int* in_sizes, int n_in,
                              void* d_out, int out_size, void* d_ws, size_t ws_size,
                              hipStream_t stream)
{
  const float* xyzf = (const float*)d_in[0];
  const float* xyzc = (const float*)d_in[1];
  const float* ff   = (const float*)d_in[2];
  const float* fc   = (const float*)d_in[3];
  const float* W1   = (const float*)d_in[4];
  const float* g1   = (const float*)d_in[6];
  const float* be1  = (const float*)d_in[7];
  const float* W2   = (const float*)d_in[8];
  const float* g2   = (const float*)d_in[10];
  const float* be2  = (const float*)d_in[11];
  float* out = (float*)d_out;

  char* ws = (char*)d_ws;
  // layout (bytes), 256-aligned. Lifetime aliasing as before.
  unsigned short* W1b  = (unsigned short*)(ws + 0);          // 163840
  unsigned short* W2b  = (unsigned short*)(ws + 163840);     // 65536
  unsigned short* X    = (unsigned short*)(ws + 229376);     // 41943040
  unsigned short* Y2b  = (unsigned short*)(ws + 229376);     // 16777216 (alias X)
  unsigned short* fcb  = (unsigned short*)(ws + 42172416);   // 8388608
  unsigned short* Y1   = (unsigned short*)(ws + 42172416);   // 33554432 (alias fcb)
  float* part1 = (float*)(ws + 75726848);                    // 1048576
  float* part2 = (float*)(ws + 76775424);                    // 524288
  float* ab1   = (float*)(ws + 77299712);                    // 2048
  float* ab2   = (float*)(ws + 77301760);                    // 1024
  float4* cpk  = (float4*)(ws + 77302784);                   // 262144
  float4* pdw  = (float4*)(ws + 77564928);                   // 1048576 (SPLIT=1)
  int4*   piw  = (int4*)  (ws + 85953536);                   // 1048576
  float4* cps  = (float4*)(ws + 88051712);                   // 262144
  float*  sxs  = (float*) (ws + 88313856);                   // 65536
  int*    lov  = (int*)   (ws + 88379392);                   // 262144
  int*    hist = (int*)   (ws + 88641536);                   // 66560
  int*    flagcnt = (int*)(ws + 88708096);                   // 256
  int*    offs = (int*)   (ws + 88708352);                   // 66560
  unsigned* perm = (unsigned*)(ws + 88774912);               // 262144
  int*    flaglist = (int*)(ws + 89037056);                  // 262144 (end ~89.3MB)

  prep<<<1024, 256, 0, stream>>>(W1, W2, xyzc, fc, W1b, W2b, cpk, fcb);
  sort_coarse<<<B_, 1024, 0, stream>>>(cpk, sxs, cps);
  hipMemsetAsync(hist, 0, B_ * NBIN_ * sizeof(int) + 256, stream);  // hist + flagcnt
  lo_hist<<<B_ * 64, 256, 0, stream>>>(xyzf, sxs, lov, hist);
  prefix_bins<<<B_, 64, 0, stream>>>(hist, offs);
  scatter_perm<<<B_ * 64, 256, 0, stream>>>(lov, offs, perm);
  nn_window<<<B_ * 256, 256, 0, stream>>>(xyzf, cps, perm, pdw, piw, flagcnt, flaglist);
  nn_brute_flag<<<512, 64, 0, stream>>>(xyzf, cpk, flagcnt, flaglist, pdw, piw);
  nn_finish<<<B_ * 256, 256, 0, stream>>>(pdw, piw, ff, fcb, X);

  // layer 1: y1 = X @ W1^T  (M=65536, N=256, K=320), stats fused
  gemm_stats<CIN_, H1_, true><<<(ROWS_/128) * (H1_/128), 256, 0, stream>>>(
      X, W1b, Y1, nullptr, part1);
  finalize_stats<<<H1_, 64, 0, stream>>>(part1, g1, be1, ab1, ROWS_/128, H1_, 1.f/ROWS_);

  // layer 2: y2 = relu(bn1(Y1)) @ W2^T with BN+ReLU fused into the A-load
  gemm_bnrelu_stats<H1_, H2_><<<(ROWS_/128) * (H2_/128), 256, 0, stream>>>(
      Y1, ab1, W2b, Y2b, part2);
  finalize_stats<<<H2_, 64, 0, stream>>>(part2, g2, be2, ab2, ROWS_/128, H2_, 1.f/ROWS_);
  bnrelu_out<<<2048, 256, 0, stream>>>(Y2b, ab2, out);
}